// Round 9
// baseline (204.980 us; speedup 1.0000x reference)
//
#include <hip/hip_runtime.h>
#include <math.h>

// FAVOR+ linear attention, segment-normalized. fp32 VALU path with explicit
// 2-step register-prefetch software pipelining (r8 post-mortem: VGPR=40 =>
// compiler serialized load->wait->FMA; VALUBusy 8%).
//
// N=8192 rows, D=M=DV=128, B=64 segments (batch_seg sorted => contiguous).
//
// ws layout (floats):
//   S      [64*128*128]  per-segment Kp^T V (fully written by k_accum)
//   Ksum   [64*128]      segment sums of Kp (fully written by k_accum)
//   segmax [64]          seg max of rowmax(U_K) clamped >=0 (memset 0)
//   Qp     [8192*128]
//   UK     [8192*128]
//   hK     [8192]

#define NROWS 8192
#define DIM   128
#define NSEG  64

#define INV_D4      0.29730177875068026f   // 128^-0.25
#define INV_SQRT_M  0.08838834764831845f   // 1/sqrt(128)
#define PHI_EPS_F   1e-4f
#define NORM_EPS_F  1e-8f
// h = sum(x^2)/(2*sqrt(128)) = 0.5 * sum((x*INV_D4)^2)  (exact fold)

// 16 FMAs: acc[i] (+)= xa[i] (4 d-vals) x o0..o3 (col-vectors for d..d+3)
#define FMA4x4(acc, xa, o0, o1, o2, o3)                                   \
    acc.x = fmaf(xa.x, o0.x, acc.x); acc.x = fmaf(xa.y, o1.x, acc.x);     \
    acc.x = fmaf(xa.z, o2.x, acc.x); acc.x = fmaf(xa.w, o3.x, acc.x);     \
    acc.y = fmaf(xa.x, o0.y, acc.y); acc.y = fmaf(xa.y, o1.y, acc.y);     \
    acc.y = fmaf(xa.z, o2.y, acc.y); acc.y = fmaf(xa.w, o3.y, acc.y);     \
    acc.z = fmaf(xa.x, o0.z, acc.z); acc.z = fmaf(xa.y, o1.z, acc.z);     \
    acc.z = fmaf(xa.z, o2.z, acc.z); acc.z = fmaf(xa.w, o3.z, acc.z);     \
    acc.w = fmaf(xa.x, o0.w, acc.w); acc.w = fmaf(xa.y, o1.w, acc.w);     \
    acc.w = fmaf(xa.z, o2.w, acc.w); acc.w = fmaf(xa.w, o3.w, acc.w);

// ---------------------------------------------------------------------------
// k_phi: U = (x*INV_D4) @ omega. Grid 512 x 256 thr; block = 32 rows (first
// 256 blocks Q, rest K). LDS: the 32 scaled input rows (16 KB). omega rows
// streamed from L2 with a 2-deep register prefetch rotation (oa/ob). Lane
// owns 4 rows x 4 cols -> 64 FMA per 4 prefetched float4.
// ---------------------------------------------------------------------------
__global__ __launch_bounds__(256, 2) void k_phi(
    const float* __restrict__ Q, const float* __restrict__ K,
    const float* __restrict__ omega, const int* __restrict__ seg,
    float* __restrict__ Qp, float* __restrict__ UK,
    float* __restrict__ hK, int* __restrict__ segmax)
{
    __shared__ float xs[32][DIM];    // 16 KB

    const int t = threadIdx.x;
    const int bid = blockIdx.x;
    const bool isQ = bid < 256;
    const int rowbase = (isQ ? bid : bid - 256) * 32;
    const float* X = (isQ ? Q : K) + (size_t)rowbase * DIM;

    // stage 32 rows scaled by INV_D4 (1024 float4, 4/thread, coalesced)
    {
        const float4* xg = (const float4*)X;
        float4* xd = (float4*)&xs[0][0];
#pragma unroll
        for (int s = 0; s < 4; ++s) {
            float4 v = xg[t + s * 256];
            v.x *= INV_D4; v.y *= INV_D4; v.z *= INV_D4; v.w *= INV_D4;
            xd[t + s * 256] = v;
        }
    }
    __syncthreads();

    const int w = t >> 6, lane = t & 63;
    const int rg = lane >> 5, cl = lane & 31;
    // lane's 4 block-local rows: w*8 + 2*i + rg
    int r[4];
#pragma unroll
    for (int i = 0; i < 4; ++i) r[i] = w * 8 + 2 * i + rg;

    // h_i = 0.5 * sum(xs[r_i]^2), reduced over the 32 cl-lanes
    float h[4];
#pragma unroll
    for (int i = 0; i < 4; ++i) {
        const float4 a = *(const float4*)&xs[r[i]][cl * 4];
        float p = a.x * a.x + a.y * a.y + a.z * a.z + a.w * a.w;
#pragma unroll
        for (int m = 1; m < 32; m <<= 1) p += __shfl_xor(p, m, 64);
        h[i] = 0.5f * p;
    }

    float4 acc[4];
#pragma unroll
    for (int i = 0; i < 4; ++i) acc[i] = make_float4(0.f, 0.f, 0.f, 0.f);

    // omega as float4 rows: og[d*32 + cl] = omega[d][cl*4..cl*4+3]
    const float4* og = (const float4*)omega;
    float4 oa0, oa1, oa2, oa3, ob0, ob1, ob2, ob3;
    oa0 = og[0 * 32 + cl]; oa1 = og[1 * 32 + cl];
    oa2 = og[2 * 32 + cl]; oa3 = og[3 * 32 + cl];
    ob0 = og[4 * 32 + cl]; ob1 = og[5 * 32 + cl];
    ob2 = og[6 * 32 + cl]; ob3 = og[7 * 32 + cl];

#pragma unroll 1
    for (int d = 0; d < DIM; d += 8) {
        // ---- half A: d..d+3 uses oa ----
        {
            float4 xa0 = *(const float4*)&xs[r[0]][d];
            float4 xa1 = *(const float4*)&xs[r[1]][d];
            float4 xa2 = *(const float4*)&xs[r[2]][d];
            float4 xa3 = *(const float4*)&xs[r[3]][d];
            FMA4x4(acc[0], xa0, oa0, oa1, oa2, oa3);
            FMA4x4(acc[1], xa1, oa0, oa1, oa2, oa3);
            FMA4x4(acc[2], xa2, oa0, oa1, oa2, oa3);
            FMA4x4(acc[3], xa3, oa0, oa1, oa2, oa3);
        }
        {   // prefetch d+8 into oa (wraps harmlessly on last iter)
            const int dn = (d + 8) & 127;
            oa0 = og[(dn + 0) * 32 + cl]; oa1 = og[(dn + 1) * 32 + cl];
            oa2 = og[(dn + 2) * 32 + cl]; oa3 = og[(dn + 3) * 32 + cl];
        }
        // ---- half B: d+4..d+7 uses ob ----
        {
            float4 xb0 = *(const float4*)&xs[r[0]][d + 4];
            float4 xb1 = *(const float4*)&xs[r[1]][d + 4];
            float4 xb2 = *(const float4*)&xs[r[2]][d + 4];
            float4 xb3 = *(const float4*)&xs[r[3]][d + 4];
            FMA4x4(acc[0], xb0, ob0, ob1, ob2, ob3);
            FMA4x4(acc[1], xb1, ob0, ob1, ob2, ob3);
            FMA4x4(acc[2], xb2, ob0, ob1, ob2, ob3);
            FMA4x4(acc[3], xb3, ob0, ob1, ob2, ob3);
        }
        {   // prefetch d+12 into ob
            const int dn = (d + 12) & 127;
            ob0 = og[(dn + 0) * 32 + cl]; ob1 = og[(dn + 1) * 32 + cl];
            ob2 = og[(dn + 2) * 32 + cl]; ob3 = og[(dn + 3) * 32 + cl];
        }
    }

    // rowmax over 128 cols
    float mx[4];
#pragma unroll
    for (int i = 0; i < 4; ++i) {
        float m = fmaxf(fmaxf(acc[i].x, acc[i].y), fmaxf(acc[i].z, acc[i].w));
#pragma unroll
        for (int s = 1; s < 32; s <<= 1) m = fmaxf(m, __shfl_xor(m, s, 64));
        mx[i] = m;
    }

#pragma unroll
    for (int i = 0; i < 4; ++i) {
        const int gr = rowbase + r[i];
        if (isQ) {
            const float b = h[i] + mx[i];
            float4 o;
            o.x = (__expf(acc[i].x - b) + PHI_EPS_F) * INV_SQRT_M;
            o.y = (__expf(acc[i].y - b) + PHI_EPS_F) * INV_SQRT_M;
            o.z = (__expf(acc[i].z - b) + PHI_EPS_F) * INV_SQRT_M;
            o.w = (__expf(acc[i].w - b) + PHI_EPS_F) * INV_SQRT_M;
            *(float4*)&Qp[(size_t)gr * DIM + cl * 4] = o;
        } else {
            *(float4*)&UK[(size_t)gr * DIM + cl * 4] = acc[i];
            if (cl == 0) {
                hK[gr] = h[i];
                if (mx[i] > 0.f)   // zero-init implements max(.,0) clamp
                    atomicMax(&segmax[seg[gr]], __float_as_int(mx[i]));
            }
        }
    }
}

// ---------------------------------------------------------------------------
// k_accum (round-6 v2, unchanged 3rd round): per (seg, 32x32 tile) block.
// ---------------------------------------------------------------------------
__global__ __launch_bounds__(256, 4) void k_accum(
    const float* __restrict__ UK, const float* __restrict__ hK,
    const float* __restrict__ V, const int* __restrict__ seg,
    const float* __restrict__ segmaxf,
    float* __restrict__ S, float* __restrict__ Ksum)
{
    __shared__ float kp[32][32];
    __shared__ float vv[32][32];

    const int t = threadIdx.x;
    const int sid  = blockIdx.x >> 4;
    const int tile = blockIdx.x & 15;
    const int tm = (tile >> 2) * 32;
    const int tv = (tile & 3) * 32;

    int start, end;
    {
        int a = 0, b = NROWS;
        while (a < b) { int m = (a + b) >> 1; if (seg[m] < sid) a = m + 1; else b = m; }
        start = a; b = NROWS;
        while (a < b) { int m = (a + b) >> 1; if (seg[m] < sid + 1) a = m + 1; else b = m; }
        end = a;
    }

    const float smax = segmaxf[sid];
    const int rs = t >> 3;
    const int cs = (t & 7) * 4;
    const int ty = t >> 4;
    const int tx = t & 15;

    float a00 = 0.f, a01 = 0.f, a10 = 0.f, a11 = 0.f;
    float4 ksl = make_float4(0.f, 0.f, 0.f, 0.f);

    for (int j = start; j < end; j += 32) {
        const int row = j + rs;
        float4 kpv = make_float4(0.f, 0.f, 0.f, 0.f);
        float4 vvv = make_float4(0.f, 0.f, 0.f, 0.f);
        if (row < end) {
            const float4 u = *(const float4*)&UK[(size_t)row * DIM + tm + cs];
            const float h = hK[row] + smax;
            kpv.x = (__expf(u.x - h) + PHI_EPS_F) * INV_SQRT_M;
            kpv.y = (__expf(u.y - h) + PHI_EPS_F) * INV_SQRT_M;
            kpv.z = (__expf(u.z - h) + PHI_EPS_F) * INV_SQRT_M;
            kpv.w = (__expf(u.w - h) + PHI_EPS_F) * INV_SQRT_M;
            vvv = *(const float4*)&V[(size_t)row * DIM + tv + cs];
        }
        __syncthreads();
        *(float4*)&kp[rs][cs] = kpv;
        *(float4*)&vv[rs][cs] = vvv;
        ksl.x += kpv.x; ksl.y += kpv.y; ksl.z += kpv.z; ksl.w += kpv.w;
        __syncthreads();
#pragma unroll
        for (int k = 0; k < 32; ++k) {
            const float2 ka = *(const float2*)&kp[k][ty * 2];
            const float2 vb = *(const float2*)&vv[k][tx * 2];
            a00 = fmaf(ka.x, vb.x, a00);
            a01 = fmaf(ka.x, vb.y, a01);
            a10 = fmaf(ka.y, vb.x, a10);
            a11 = fmaf(ka.y, vb.y, a11);
        }
    }

    float* Sseg = S + (size_t)sid * DIM * DIM;
    {
        float2 r0; r0.x = a00; r0.y = a01;
        float2 r1; r1.x = a10; r1.y = a11;
        *(float2*)&Sseg[(tm + 2 * ty + 0) * DIM + tv + 2 * tx] = r0;
        *(float2*)&Sseg[(tm + 2 * ty + 1) * DIM + tv + 2 * tx] = r1;
    }

    __syncthreads();
    *(float4*)&kp[rs][cs] = ksl;
    __syncthreads();
    if (tv == 0 && t < 32) {
        float s = 0.f;
#pragma unroll
        for (int r = 0; r < 32; ++r) s += kp[r][t];
        Ksum[sid * DIM + tm + t] = s;
    }
}

// ---------------------------------------------------------------------------
// k_out: out_i = (Qp_i @ S[seg_i]) / (Qp_i . Ksum[seg_i] + eps).
// Segment-aligned: grid = 64 segs x 8 chunks of 32 rows => one S per block,
// lane owns 4 rows x 4 cols (64 FMA per 4 S-loads), 2-deep S prefetch.
// ---------------------------------------------------------------------------
__global__ __launch_bounds__(256, 2) void k_out(
    const float* __restrict__ Qp, const float* __restrict__ S,
    const float* __restrict__ Ksum, const int* __restrict__ seg,
    float* __restrict__ out)
{
    __shared__ float qs[32][DIM];    // 16 KB

    const int t = threadIdx.x;
    const int sid = blockIdx.x >> 3, part = blockIdx.x & 7;

    int start, end;
    {
        int a = 0, b = NROWS;
        while (a < b) { int m = (a + b) >> 1; if (seg[m] < sid) a = m + 1; else b = m; }
        start = a; b = NROWS;
        while (a < b) { int m = (a + b) >> 1; if (seg[m] < sid + 1) a = m + 1; else b = m; }
        end = a;
    }

    const int w = t >> 6, lane = t & 63;
    const int rg = lane >> 5, cl = lane & 31;
    int r[4];
#pragma unroll
    for (int i = 0; i < 4; ++i) r[i] = w * 8 + 2 * i + rg;

    const float4 ks = *(const float4*)&Ksum[sid * DIM + cl * 4];  // invariant
    const float4* sg = (const float4*)(S + (size_t)sid * DIM * DIM);

    for (int base = start + part * 32; base < end; base += 256) {
        __syncthreads();   // previous chunk's qs reads must be done
        {   // stage up to 32 Qp rows (clamp overrun rows; unused at store)
            float4* xd = (float4*)&qs[0][0];
#pragma unroll
            for (int s = 0; s < 4; ++s) {
                const int idx = t + s * 256;
                const int grow = min(base + (idx >> 5), end - 1);
                xd[idx] = ((const float4*)(Qp + (size_t)grow * DIM))[idx & 31];
            }
        }
        __syncthreads();

        // norms: n_i = Qp_row . Ksum[sid] + eps
        float n[4];
#pragma unroll
        for (int i = 0; i < 4; ++i) {
            const float4 q = *(const float4*)&qs[r[i]][cl * 4];
            float p = q.x * ks.x + q.y * ks.y + q.z * ks.z + q.w * ks.w;
#pragma unroll
            for (int m = 1; m < 32; m <<= 1) p += __shfl_xor(p, m, 64);
            n[i] = p + NORM_EPS_F;
        }

        float4 acc[4];
#pragma unroll
        for (int i = 0; i < 4; ++i) acc[i] = make_float4(0.f, 0.f, 0.f, 0.f);

        float4 sa0, sa1, sa2, sa3, sb0, sb1, sb2, sb3;
        sa0 = sg[0 * 32 + cl]; sa1 = sg[1 * 32 + cl];
        sa2 = sg[2 * 32 + cl]; sa3 = sg[3 * 32 + cl];
        sb0 = sg[4 * 32 + cl]; sb1 = sg[5 * 32 + cl];
        sb2 = sg[6 * 32 + cl]; sb3 = sg[7 * 32 + cl];

#pragma unroll 1
        for (int m = 0; m < DIM; m += 8) {
            {
                float4 xa0 = *(const float4*)&qs[r[0]][m];
                float4 xa1 = *(const float4*)&qs[r[1]][m];
                float4 xa2 = *(const float4*)&qs[r[2]][m];
                float4 xa3 = *(const float4*)&qs[r[3]][m];
                FMA4x4(acc[0], xa0, sa0, sa1, sa2, sa3);
                FMA4x4(acc[1], xa1, sa0, sa1, sa2, sa3);
                FMA4x4(acc[2], xa2, sa0, sa1, sa2, sa3);
                FMA4x4(acc[3], xa3, sa0, sa1, sa2, sa3);
            }
            {
                const int mn = (m + 8) & 127;
                sa0 = sg[(mn + 0) * 32 + cl]; sa1 = sg[(mn + 1) * 32 + cl];
                sa2 = sg[(mn + 2) * 32 + cl]; sa3 = sg[(mn + 3) * 32 + cl];
            }
            {
                float4 xb0 = *(const float4*)&qs[r[0]][m + 4];
                float4 xb1 = *(const float4*)&qs[r[1]][m + 4];
                float4 xb2 = *(const float4*)&qs[r[2]][m + 4];
                float4 xb3 = *(const float4*)&qs[r[3]][m + 4];
                FMA4x4(acc[0], xb0, sb0, sb1, sb2, sb3);
                FMA4x4(acc[1], xb1, sb0, sb1, sb2, sb3);
                FMA4x4(acc[2], xb2, sb0, sb1, sb2, sb3);
                FMA4x4(acc[3], xb3, sb0, sb1, sb2, sb3);
            }
            {
                const int mn = (m + 12) & 127;
                sb0 = sg[(mn + 0) * 32 + cl]; sb1 = sg[(mn + 1) * 32 + cl];
                sb2 = sg[(mn + 2) * 32 + cl]; sb3 = sg[(mn + 3) * 32 + cl];
            }
        }

#pragma unroll
        for (int i = 0; i < 4; ++i) {
            const int gr = base + r[i];
            if (gr < end) {
                const float inv = 1.0f / n[i];
                float4 o;
                o.x = acc[i].x * inv; o.y = acc[i].y * inv;
                o.z = acc[i].z * inv; o.w = acc[i].w * inv;
                *(float4*)&out[(size_t)gr * DIM + cl * 4] = o;
            }
        }
    }
}

// ---------------------------------------------------------------------------
extern "C" void kernel_launch(void* const* d_in, const int* in_sizes, int n_in,
                              void* d_out, int out_size, void* d_ws, size_t ws_size,
                              hipStream_t stream)
{
    const float* Q     = (const float*)d_in[0];
    const float* K     = (const float*)d_in[1];
    const float* V     = (const float*)d_in[2];
    const float* omega = (const float*)d_in[3];
    const int*   seg   = (const int*)d_in[4];
    float* out = (float*)d_out;

    float* ws      = (float*)d_ws;
    float* S       = ws;
    float* Ksum    = S + (size_t)NSEG * DIM * DIM;
    float* segmaxf = Ksum + NSEG * DIM;
    float* Qp      = segmaxf + NSEG;
    float* UK      = Qp + (size_t)NROWS * DIM;
    float* hK      = UK + (size_t)NROWS * DIM;

    hipMemsetAsync(segmaxf, 0, NSEG * sizeof(float), stream);

    hipLaunchKernelGGL(k_phi, dim3(512), dim3(256), 0, stream,
                       Q, K, omega, seg, Qp, UK, hK, (int*)segmaxf);
    hipLaunchKernelGGL(k_accum, dim3(NSEG * 16), dim3(256), 0, stream,
                       UK, hK, V, seg, segmaxf, S, Ksum);
    hipLaunchKernelGGL(k_out, dim3(NSEG * 8), dim3(256), 0, stream,
                       Qp, S, Ksum, seg, out);
}

// Round 12
// 154.058 us; speedup vs baseline: 1.3305x; 1.3305x over previous
//
#include <hip/hip_runtime.h>
#include <math.h>

// FAVOR+ linear attention, segment-normalized. fp32 VALU path.
// Round-10 structure: fat register tiles (4 rows x 8 cols = 32 acc/lane,
// 128 FMA per 12 LDS reads) so a single wave self-hides LDS latency.
// k_phi/k_out: 1 block/CU, 96KB LDS (operand matrix + row panel).
// k_accum: round-6 v2, byte-identical (control).
//
// ws layout (floats):
//   S      [64*128*128]  per-segment Kp^T V (fully written by k_accum)
//   Ksum   [64*128]      segment sums of Kp (fully written by k_accum)
//   segmax [64]          seg max of rowmax(U_K) clamped >=0 (memset 0)
//   Qp     [8192*128]
//   UK     [8192*128]
//   hK     [8192]

#define NROWS 8192
#define DIM   128
#define NSEG  64

#define INV_D4      0.29730177875068026f   // 128^-0.25
#define INV_SQRT_M  0.08838834764831845f   // 1/sqrt(128)
#define PHI_EPS_F   1e-4f
#define NORM_EPS_F  1e-8f
// h = sum(x^2)/(2*sqrt(128)) = 0.5 * sum((x*INV_D4)^2)  (exact fold)

// ---------------------------------------------------------------------------
// k_phi: U = (x*INV_D4) @ omega. Grid 256 x 256 thr; block = 64 rows (first
// 128 blocks Q, rest K). LDS: omega 64KB + 64 scaled rows 32KB. Lane owns
// 4 rows x 8 cols; per d-step(4): 128 FMA vs 8 om-reads + 4 row-broadcasts.
// ---------------------------------------------------------------------------
__global__ __launch_bounds__(256, 1) void k_phi(
    const float* __restrict__ Q, const float* __restrict__ K,
    const float* __restrict__ omega, const int* __restrict__ seg,
    float* __restrict__ Qp, float* __restrict__ UK,
    float* __restrict__ hK, int* __restrict__ segmax)
{
    __shared__ float om[DIM * DIM];   // 64 KB
    __shared__ float xs[64][DIM];     // 32 KB

    const int t = threadIdx.x;
    const int bid = blockIdx.x;
    const bool isQ = bid < 128;
    const int rowbase = (isQ ? bid : bid - 128) * 64;
    const float* X = (isQ ? Q : K) + (size_t)rowbase * DIM;

    {   // stage omega: 4096 float4, 16/thread, coalesced
        const float4* src = (const float4*)omega;
        float4* dst = (float4*)om;
#pragma unroll
        for (int i = 0; i < 16; ++i) dst[t + i * 256] = src[t + i * 256];
    }
    {   // stage 64 rows scaled by INV_D4: 2048 float4, 8/thread
        const float4* xg = (const float4*)X;
        float4* xd = (float4*)&xs[0][0];
#pragma unroll
        for (int s = 0; s < 8; ++s) {
            float4 v = xg[t + s * 256];
            v.x *= INV_D4; v.y *= INV_D4; v.z *= INV_D4; v.w *= INV_D4;
            xd[t + s * 256] = v;
        }
    }
    __syncthreads();

    const int w = t >> 6, l = t & 63;
    const int q = l >> 4;            // row quad 0..3
    const int c = (l & 15) * 8;      // cols c..c+7
    int r[4];
#pragma unroll
    for (int i = 0; i < 4; ++i) r[i] = w * 16 + q * 4 + i;   // block-local

    // h_i = 0.5*sum(xs[r_i]^2): 8-col partial + xor-reduce over the 16 lanes
    float h[4];
#pragma unroll
    for (int i = 0; i < 4; ++i) {
        const float4 a = *(const float4*)&xs[r[i]][c];
        const float4 b = *(const float4*)&xs[r[i]][c + 4];
        float p = a.x * a.x + a.y * a.y + a.z * a.z + a.w * a.w
                + b.x * b.x + b.y * b.y + b.z * b.z + b.w * b.w;
        p += __shfl_xor(p, 1); p += __shfl_xor(p, 2);
        p += __shfl_xor(p, 4); p += __shfl_xor(p, 8);
        h[i] = 0.5f * p;
    }

    float acc[4][8];
#pragma unroll
    for (int i = 0; i < 4; ++i)
#pragma unroll
        for (int n = 0; n < 8; ++n) acc[i][n] = 0.f;

#pragma unroll 1
    for (int d = 0; d < DIM; d += 4) {
        float4 oA[4], oB[4];     // om[d+j][c..c+7]
#pragma unroll
        for (int j = 0; j < 4; ++j) {
            oA[j] = *(const float4*)&om[(d + j) * DIM + c];
            oB[j] = *(const float4*)&om[(d + j) * DIM + c + 4];
        }
        float4 xr[4];            // xs[r_i][d..d+3] (broadcast)
#pragma unroll
        for (int i = 0; i < 4; ++i) xr[i] = *(const float4*)&xs[r[i]][d];
#pragma unroll
        for (int i = 0; i < 4; ++i) {
            const float xv[4] = {xr[i].x, xr[i].y, xr[i].z, xr[i].w};
#pragma unroll
            for (int j = 0; j < 4; ++j) {
                acc[i][0] = fmaf(xv[j], oA[j].x, acc[i][0]);
                acc[i][1] = fmaf(xv[j], oA[j].y, acc[i][1]);
                acc[i][2] = fmaf(xv[j], oA[j].z, acc[i][2]);
                acc[i][3] = fmaf(xv[j], oA[j].w, acc[i][3]);
                acc[i][4] = fmaf(xv[j], oB[j].x, acc[i][4]);
                acc[i][5] = fmaf(xv[j], oB[j].y, acc[i][5]);
                acc[i][6] = fmaf(xv[j], oB[j].z, acc[i][6]);
                acc[i][7] = fmaf(xv[j], oB[j].w, acc[i][7]);
            }
        }
    }

    // rowmax over 128 cols: 8-reg max + xor-reduce over the 16 lanes
    float mx[4];
#pragma unroll
    for (int i = 0; i < 4; ++i) {
        float m = acc[i][0];
#pragma unroll
        for (int n = 1; n < 8; ++n) m = fmaxf(m, acc[i][n]);
        m = fmaxf(m, __shfl_xor(m, 1)); m = fmaxf(m, __shfl_xor(m, 2));
        m = fmaxf(m, __shfl_xor(m, 4)); m = fmaxf(m, __shfl_xor(m, 8));
        mx[i] = m;
    }

#pragma unroll
    for (int i = 0; i < 4; ++i) {
        const int gr = rowbase + r[i];
        if (isQ) {
            const float b = h[i] + mx[i];
            float4 e0, e1;
            e0.x = (__expf(acc[i][0] - b) + PHI_EPS_F) * INV_SQRT_M;
            e0.y = (__expf(acc[i][1] - b) + PHI_EPS_F) * INV_SQRT_M;
            e0.z = (__expf(acc[i][2] - b) + PHI_EPS_F) * INV_SQRT_M;
            e0.w = (__expf(acc[i][3] - b) + PHI_EPS_F) * INV_SQRT_M;
            e1.x = (__expf(acc[i][4] - b) + PHI_EPS_F) * INV_SQRT_M;
            e1.y = (__expf(acc[i][5] - b) + PHI_EPS_F) * INV_SQRT_M;
            e1.z = (__expf(acc[i][6] - b) + PHI_EPS_F) * INV_SQRT_M;
            e1.w = (__expf(acc[i][7] - b) + PHI_EPS_F) * INV_SQRT_M;
            *(float4*)&Qp[(size_t)gr * DIM + c]     = e0;
            *(float4*)&Qp[(size_t)gr * DIM + c + 4] = e1;
        } else {
            float4 u0, u1;
            u0.x = acc[i][0]; u0.y = acc[i][1]; u0.z = acc[i][2]; u0.w = acc[i][3];
            u1.x = acc[i][4]; u1.y = acc[i][5]; u1.z = acc[i][6]; u1.w = acc[i][7];
            *(float4*)&UK[(size_t)gr * DIM + c]     = u0;
            *(float4*)&UK[(size_t)gr * DIM + c + 4] = u1;
            if ((l & 15) == 0) {
                hK[gr] = h[i];
                if (mx[i] > 0.f)   // zero-init implements max(.,0) clamp
                    atomicMax(&segmax[seg[gr]], __float_as_int(mx[i]));
            }
        }
    }
}

// ---------------------------------------------------------------------------
// k_accum (round-6 v2, unchanged — control): per (seg, 32x32 tile) block.
// ---------------------------------------------------------------------------
__global__ __launch_bounds__(256, 4) void k_accum(
    const float* __restrict__ UK, const float* __restrict__ hK,
    const float* __restrict__ V, const int* __restrict__ seg,
    const float* __restrict__ segmaxf,
    float* __restrict__ S, float* __restrict__ Ksum)
{
    __shared__ float kp[32][32];
    __shared__ float vv[32][32];

    const int t = threadIdx.x;
    const int sid  = blockIdx.x >> 4;
    const int tile = blockIdx.x & 15;
    const int tm = (tile >> 2) * 32;
    const int tv = (tile & 3) * 32;

    int start, end;
    {
        int a = 0, b = NROWS;
        while (a < b) { int m = (a + b) >> 1; if (seg[m] < sid) a = m + 1; else b = m; }
        start = a; b = NROWS;
        while (a < b) { int m = (a + b) >> 1; if (seg[m] < sid + 1) a = m + 1; else b = m; }
        end = a;
    }

    const float smax = segmaxf[sid];
    const int rs = t >> 3;
    const int cs = (t & 7) * 4;
    const int ty = t >> 4;
    const int tx = t & 15;

    float a00 = 0.f, a01 = 0.f, a10 = 0.f, a11 = 0.f;
    float4 ksl = make_float4(0.f, 0.f, 0.f, 0.f);

    for (int j = start; j < end; j += 32) {
        const int row = j + rs;
        float4 kpv = make_float4(0.f, 0.f, 0.f, 0.f);
        float4 vvv = make_float4(0.f, 0.f, 0.f, 0.f);
        if (row < end) {
            const float4 u = *(const float4*)&UK[(size_t)row * DIM + tm + cs];
            const float h = hK[row] + smax;
            kpv.x = (__expf(u.x - h) + PHI_EPS_F) * INV_SQRT_M;
            kpv.y = (__expf(u.y - h) + PHI_EPS_F) * INV_SQRT_M;
            kpv.z = (__expf(u.z - h) + PHI_EPS_F) * INV_SQRT_M;
            kpv.w = (__expf(u.w - h) + PHI_EPS_F) * INV_SQRT_M;
            vvv = *(const float4*)&V[(size_t)row * DIM + tv + cs];
        }
        __syncthreads();
        *(float4*)&kp[rs][cs] = kpv;
        *(float4*)&vv[rs][cs] = vvv;
        ksl.x += kpv.x; ksl.y += kpv.y; ksl.z += kpv.z; ksl.w += kpv.w;
        __syncthreads();
#pragma unroll
        for (int k = 0; k < 32; ++k) {
            const float2 ka = *(const float2*)&kp[k][ty * 2];
            const float2 vb = *(const float2*)&vv[k][tx * 2];
            a00 = fmaf(ka.x, vb.x, a00);
            a01 = fmaf(ka.x, vb.y, a01);
            a10 = fmaf(ka.y, vb.x, a10);
            a11 = fmaf(ka.y, vb.y, a11);
        }
    }

    float* Sseg = S + (size_t)sid * DIM * DIM;
    {
        float2 r0; r0.x = a00; r0.y = a01;
        float2 r1; r1.x = a10; r1.y = a11;
        *(float2*)&Sseg[(tm + 2 * ty + 0) * DIM + tv + 2 * tx] = r0;
        *(float2*)&Sseg[(tm + 2 * ty + 1) * DIM + tv + 2 * tx] = r1;
    }

    __syncthreads();
    *(float4*)&kp[rs][cs] = ksl;
    __syncthreads();
    if (tv == 0 && t < 32) {
        float s = 0.f;
#pragma unroll
        for (int r = 0; r < 32; ++r) s += kp[r][t];
        Ksum[sid * DIM + tm + t] = s;
    }
}

// ---------------------------------------------------------------------------
// k_out: out_i = (Qp_i @ S[seg_i]) / (Qp_i . Ksum[seg_i] + eps).
// Grid 64 segs x 4 chunks of 64 rows; S[seg] 64KB + 64 Qp rows 32KB in LDS;
// same 4x8 register tile. Grid-stride chunk loop as safety for huge segs.
// ---------------------------------------------------------------------------
__global__ __launch_bounds__(256, 1) void k_out(
    const float* __restrict__ Qp, const float* __restrict__ S,
    const float* __restrict__ Ksum, const int* __restrict__ seg,
    float* __restrict__ out)
{
    __shared__ float Sl[DIM * DIM];   // 64 KB
    __shared__ float qs[64][DIM];     // 32 KB
    __shared__ float Ks[DIM];

    const int t = threadIdx.x;
    const int sid = blockIdx.x >> 2, chunk = blockIdx.x & 3;

    int start, end;
    {
        int a = 0, b = NROWS;
        while (a < b) { int m = (a + b) >> 1; if (seg[m] < sid) a = m + 1; else b = m; }
        start = a; b = NROWS;
        while (a < b) { int m = (a + b) >> 1; if (seg[m] < sid + 1) a = m + 1; else b = m; }
        end = a;
    }

    {   // stage S[sid] + Ksum[sid] once
        const float4* src = (const float4*)(S + (size_t)sid * DIM * DIM);
        float4* dst = (float4*)Sl;
#pragma unroll
        for (int i = 0; i < 16; ++i) dst[t + i * 256] = src[t + i * 256];
        if (t < DIM) Ks[t] = Ksum[sid * DIM + t];
    }

    const int w = t >> 6, l = t & 63;
    const int q = l >> 4;
    const int c = (l & 15) * 8;
    int r[4];
#pragma unroll
    for (int i = 0; i < 4; ++i) r[i] = w * 16 + q * 4 + i;

    for (int base = start + chunk * 64; base < end; base += 256) {
        __syncthreads();   // Sl ready (1st iter) / prior qs reads done
        {   // stage up to 64 Qp rows (clamp overrun; guarded at store)
            float4* xd = (float4*)&qs[0][0];
#pragma unroll
            for (int s = 0; s < 8; ++s) {
                const int idx = t + s * 256;
                const int grow = min(base + (idx >> 5), end - 1);
                xd[idx] = ((const float4*)(Qp + (size_t)grow * DIM))[idx & 31];
            }
        }
        __syncthreads();

        // norms: n_i = qs[r_i] . Ks  (8-col partial + 16-lane xor reduce)
        float n[4];
#pragma unroll
        for (int i = 0; i < 4; ++i) {
            const float4 a = *(const float4*)&qs[r[i]][c];
            const float4 b = *(const float4*)&qs[r[i]][c + 4];
            const float4 ka = *(const float4*)&Ks[c];
            const float4 kb = *(const float4*)&Ks[c + 4];
            float p = a.x * ka.x + a.y * ka.y + a.z * ka.z + a.w * ka.w
                    + b.x * kb.x + b.y * kb.y + b.z * kb.z + b.w * kb.w;
            p += __shfl_xor(p, 1); p += __shfl_xor(p, 2);
            p += __shfl_xor(p, 4); p += __shfl_xor(p, 8);
            n[i] = p + NORM_EPS_F;
        }

        float acc[4][8];
#pragma unroll
        for (int i = 0; i < 4; ++i)
#pragma unroll
            for (int nn = 0; nn < 8; ++nn) acc[i][nn] = 0.f;

#pragma unroll 1
        for (int m = 0; m < DIM; m += 4) {
            float4 oA[4], oB[4];
#pragma unroll
            for (int j = 0; j < 4; ++j) {
                oA[j] = *(const float4*)&Sl[(m + j) * DIM + c];
                oB[j] = *(const float4*)&Sl[(m + j) * DIM + c + 4];
            }
            float4 xr[4];
#pragma unroll
            for (int i = 0; i < 4; ++i) xr[i] = *(const float4*)&qs[r[i]][m];
#pragma unroll
            for (int i = 0; i < 4; ++i) {
                const float xv[4] = {xr[i].x, xr[i].y, xr[i].z, xr[i].w};
#pragma unroll
                for (int j = 0; j < 4; ++j) {
                    acc[i][0] = fmaf(xv[j], oA[j].x, acc[i][0]);
                    acc[i][1] = fmaf(xv[j], oA[j].y, acc[i][1]);
                    acc[i][2] = fmaf(xv[j], oA[j].z, acc[i][2]);
                    acc[i][3] = fmaf(xv[j], oA[j].w, acc[i][3]);
                    acc[i][4] = fmaf(xv[j], oB[j].x, acc[i][4]);
                    acc[i][5] = fmaf(xv[j], oB[j].y, acc[i][5]);
                    acc[i][6] = fmaf(xv[j], oB[j].z, acc[i][6]);
                    acc[i][7] = fmaf(xv[j], oB[j].w, acc[i][7]);
                }
            }
        }

#pragma unroll
        for (int i = 0; i < 4; ++i) {
            const int gr = base + r[i];
            if (gr < end) {
                const float inv = 1.0f / n[i];
                float4 o0, o1;
                o0.x = acc[i][0] * inv; o0.y = acc[i][1] * inv;
                o0.z = acc[i][2] * inv; o0.w = acc[i][3] * inv;
                o1.x = acc[i][4] * inv; o1.y = acc[i][5] * inv;
                o1.z = acc[i][6] * inv; o1.w = acc[i][7] * inv;
                *(float4*)&out[(size_t)gr * DIM + c]     = o0;
                *(float4*)&out[(size_t)gr * DIM + c + 4] = o1;
            }
        }
    }
}

// ---------------------------------------------------------------------------
extern "C" void kernel_launch(void* const* d_in, const int* in_sizes, int n_in,
                              void* d_out, int out_size, void* d_ws, size_t ws_size,
                              hipStream_t stream)
{
    const float* Q     = (const float*)d_in[0];
    const float* K     = (const float*)d_in[1];
    const float* V     = (const float*)d_in[2];
    const float* omega = (const float*)d_in[3];
    const int*   seg   = (const int*)d_in[4];
    float* out = (float*)d_out;

    float* ws      = (float*)d_ws;
    float* S       = ws;
    float* Ksum    = S + (size_t)NSEG * DIM * DIM;
    float* segmaxf = Ksum + NSEG * DIM;
    float* Qp      = segmaxf + NSEG;
    float* UK      = Qp + (size_t)NROWS * DIM;
    float* hK      = UK + (size_t)NROWS * DIM;

    hipMemsetAsync(segmaxf, 0, NSEG * sizeof(float), stream);

    hipLaunchKernelGGL(k_phi, dim3(256), dim3(256), 0, stream,
                       Q, K, omega, seg, Qp, UK, hK, (int*)segmaxf);
    hipLaunchKernelGGL(k_accum, dim3(NSEG * 16), dim3(256), 0, stream,
                       UK, hK, V, seg, segmaxf, S, Ksum);
    hipLaunchKernelGGL(k_out, dim3(NSEG * 4), dim3(256), 0, stream,
                       Qp, S, Ksum, seg, out);
}